// Round 21
// baseline (763.822 us; speedup 1.0000x reference)
//
#include <hip/hip_runtime.h>
#include <stdint.h>

typedef short bf16x8 __attribute__((ext_vector_type(8)));
typedef float f32x4 __attribute__((ext_vector_type(4)));

#define BATCH 8192
#define EMBED 8192
#define U0    1024
#define U1    256
#define NHEAD 6

// ---------- helpers ----------
__device__ __forceinline__ unsigned short f2bf(float f) {
  union { float f; unsigned int u; } v; v.f = f;
  unsigned int u = v.u;
  unsigned int r = u + 0x7FFFu + ((u >> 16) & 1u);  // RNE
  return (unsigned short)(r >> 16);
}
__device__ __forceinline__ unsigned int pk2(float lo, float hi) {
  return (unsigned int)f2bf(lo) | ((unsigned int)f2bf(hi) << 16);
}
__device__ __forceinline__ void async_copy16(const void* g, void* l) {
  __builtin_amdgcn_global_load_lds((const __attribute__((address_space(1))) void*)g,
                                   (__attribute__((address_space(3))) void*)l, 16, 0, 0);
}

// ---------- kernel 1: x fp32 -> bf16 (grid-stride, 2048 blocks per G11) ----------
__global__ void cvt_x_kernel(const float* __restrict__ x, unsigned short* __restrict__ xb) {
  const long total = (long)BATCH * EMBED;
  const long stride = (long)gridDim.x * blockDim.x * 8;
  for (long i = ((long)blockIdx.x * blockDim.x + threadIdx.x) * 8; i < total; i += stride) {
    float4 a = *(const float4*)(x + i);
    float4 b = *(const float4*)(x + i + 4);
    uint4 r;
    r.x = pk2(a.x, a.y); r.y = pk2(a.z, a.w);
    r.z = pk2(b.x, b.y); r.w = pk2(b.z, b.w);
    *(uint4*)(xb + i) = r;
  }
}

// ---------- kernel 2: transpose + convert: in[R][C] fp32 -> out[C][R] bf16 ----------
__global__ void transpose_cvt_kernel(const float* __restrict__ in, unsigned short* __restrict__ out,
                                     int R, int C, long in_z, long out_z) {
  __shared__ unsigned short tile[64][65];
  const float* inp = in + (long)blockIdx.z * in_z;
  unsigned short* outp = out + (long)blockIdx.z * out_z;
  int r0 = blockIdx.x * 64;
  int c0 = blockIdx.y * 64;
  int lc = threadIdx.x & 63;
  int lr = threadIdx.x >> 6;  // 0..3
#pragma unroll
  for (int i = 0; i < 16; i++) {
    int r = lr + i * 4;
    tile[r][lc] = f2bf(inp[(long)(r0 + r) * C + (c0 + lc)]);
  }
  __syncthreads();
#pragma unroll
  for (int i = 0; i < 16; i++) {
    int c = lr + i * 4;
    outp[(long)(c0 + c) * R + (r0 + lc)] = tile[lc][c];
  }
}

// ---------- kernel 3: bucket rows by command (single block, ballot-aggregated) ----------
__global__ void bucket_kernel(const int* __restrict__ cmd, int* __restrict__ idxlist,
                              int* __restrict__ meta) {
  __shared__ int cnt[NHEAD], cur[NHEAD], off[NHEAD + 1];
  int tid = threadIdx.x;            // 1024 threads = 16 waves
  int lane = tid & 63, wave = tid >> 6;
  if (tid < NHEAD) cnt[tid] = 0;
  __syncthreads();
  for (int base = wave * 64; base < BATCH; base += 1024) {
    int c = cmd[base + lane];
#pragma unroll
    for (int h2 = 0; h2 < NHEAD; h2++) {
      unsigned long long m = __ballot(c == h2);
      if (lane == 0 && m) atomicAdd(&cnt[h2], __popcll(m));
    }
  }
  __syncthreads();
  if (tid == 0) {
    int s = 0;
    for (int h2 = 0; h2 < NHEAD; h2++) { off[h2] = s; s += cnt[h2]; }
    off[NHEAD] = s;
  }
  __syncthreads();
  if (tid < NHEAD) cur[tid] = off[tid];
  if (tid <= NHEAD) meta[tid] = off[tid];
  __syncthreads();
  for (int base = wave * 64; base < BATCH; base += 1024) {
    int b = base + lane;
    int c = cmd[b];
    int pos = 0;
#pragma unroll
    for (int h2 = 0; h2 < NHEAD; h2++) {
      unsigned long long m = __ballot(c == h2);
      if (m) {
        int leader = (int)(__ffsll((unsigned long long)m) - 1);
        int wbase = 0;
        if (lane == leader) wbase = atomicAdd(&cur[h2], __popcll(m));
        wbase = __shfl(wbase, leader);
        if (c == h2) pos = wbase + __popcll(m & ((1ULL << lane) - 1ULL));
      }
    }
    idxlist[pos] = b;
  }
}

// ---------- kernel 4: GEMM  h = relu(xb @ fc_W + fc_b), 2-phase, NAMED buffers ----------
// R19's unified As[2][..] with runtime cur forced the compiler to insert
// s_waitcnt vmcnt(0) BEFORE the ds_reads (can't disprove aliasing between the
// in-flight global_load_lds writes and the reads) -> serialized == 1-phase (null).
// Fix: 4 distinct __shared__ objects + k-loop unrolled x2 so read/write buffers
// are compile-time distinct; step order = ds_read ks0 -> stage t+1 -> MFMA ks0 ->
// ds_read ks1 -> MFMA ks1 -> asm vmcnt(0) -> raw s_barrier (T3/T4 placement).
// Safety: each wave's ds_reads drain via compiler lgkmcnt before its MFMAs; its
// DMA writes drain via the explicit vmcnt(0); barrier then makes both global.
__global__ __launch_bounds__(512) void gemm_kernel(const unsigned short* __restrict__ xb,
                                                   const unsigned short* __restrict__ wt,
                                                   const float* __restrict__ fc_b,
                                                   unsigned short* __restrict__ h) {
  __shared__ uint4 As0[1024];  // 16 KB each: slot ((wm*2+ks)*2+mi)*64 + lane
  __shared__ uint4 Bs0[1024];
  __shared__ uint4 As1[1024];
  __shared__ uint4 Bs1[1024];
  int tid  = threadIdx.x;
  int lane = tid & 63;
  int wave = tid >> 6;        // 0..7
  int wm = wave >> 1;         // 0..3
  int wn = wave & 1;          // 0..1

  int f = blockIdx.x;         // 0..511
  int xcd = f & 7;
  int idx = f >> 3;           // 0..63
  int by = xcd * 8 + (idx >> 3);
  int bx = idx & 7;
  int m0 = by * 128;
  int n0 = bx * 128;
  int l15 = lane & 15, lq = lane >> 4;

  // staging: 2048 slots over 512 lanes = 2 A-copies + 2 B-copies per lane.
  long asrc[2], bsrc[2];
  int aslot[2], bslot[2];
#pragma unroll
  for (int j = 0; j < 2; j++) {
    int ca = wave * 2 + j;                 // 0..15 = (cwm*2+cks)*2+cmi
    int cwm = ca >> 2, cka = (ca >> 1) & 1, cmi = ca & 1;
    asrc[j] = (long)(m0 + cwm * 32 + cmi * 16 + l15) * EMBED + cka * 32 + lq * 8;
    aslot[j] = ca * 64 + lane;
    int cb = wave * 2 + j;                 // 0..15 = (cwn*2+cks)*4+cni
    int cwn = cb >> 3, ckb = (cb >> 2) & 1, cni = cb & 3;
    bsrc[j] = (long)(n0 + cwn * 64 + cni * 16 + l15) * EMBED + ckb * 32 + lq * 8;
    bslot[j] = cb * 64 + lane;
  }

  f32x4 zero = {0.f, 0.f, 0.f, 0.f};
  f32x4 acc[2][4];
#pragma unroll
  for (int mi = 0; mi < 2; mi++)
#pragma unroll
    for (int ni = 0; ni < 4; ni++) acc[mi][ni] = zero;

  // prologue: stage tile 0 into buf0
#pragma unroll
  for (int j = 0; j < 2; j++) {
    async_copy16(xb + asrc[j], &As0[aslot[j]]);
    async_copy16(wt + bsrc[j], &Bs0[bslot[j]]);
  }
  asm volatile("s_waitcnt vmcnt(0)" ::: "memory");
  __builtin_amdgcn_s_barrier();

  // one k-step: read RA/RB (tile t), prefetch tile t+1 into WA/WB, MFMA, sync.
#define GEMM_STEP(RA, RB, WA, WB, PREF, KNEXT)                                      \
  {                                                                                 \
    bf16x8 af[2], bfr[4];                                                           \
    /* ks=0 fragment reads (from RA/RB: distinct objects from WA/WB) */             \
    _Pragma("unroll")                                                               \
    for (int mi = 0; mi < 2; mi++) af[mi] = *(const bf16x8*)&RA[(0 * 2 + mi + wm * 4) * 64 + lane]; \
    _Pragma("unroll")                                                               \
    for (int ni = 0; ni < 4; ni++) bfr[ni] = *(const bf16x8*)&RB[(0 * 4 + ni + wn * 8) * 64 + lane]; \
    /* issue next-tile stage early: overlaps MFMA ks0 + reads ks1 + MFMA ks1 */     \
    if (PREF) {                                                                     \
      _Pragma("unroll")                                                             \
      for (int j = 0; j < 2; j++) {                                                 \
        async_copy16(xb + asrc[j] + (KNEXT), &WA[aslot[j]]);                        \
        async_copy16(wt + bsrc[j] + (KNEXT), &WB[bslot[j]]);                        \
      }                                                                             \
    }                                                                               \
    _Pragma("unroll")                                                               \
    for (int mi = 0; mi < 2; mi++)                                                  \
      _Pragma("unroll")                                                             \
      for (int ni = 0; ni < 4; ni++)                                                \
        acc[mi][ni] = __builtin_amdgcn_mfma_f32_16x16x32_bf16(af[mi], bfr[ni], acc[mi][ni], 0, 0, 0); \
    /* ks=1 */                                                                      \
    _Pragma("unroll")                                                               \
    for (int mi = 0; mi < 2; mi++) af[mi] = *(const bf16x8*)&RA[(1 * 2 + mi + wm * 4) * 64 + lane]; \
    _Pragma("unroll")                                                               \
    for (int ni = 0; ni < 4; ni++) bfr[ni] = *(const bf16x8*)&RB[(1 * 4 + ni + wn * 8) * 64 + lane]; \
    _Pragma("unroll")                                                               \
    for (int mi = 0; mi < 2; mi++)                                                  \
      _Pragma("unroll")                                                             \
      for (int ni = 0; ni < 4; ni++)                                                \
        acc[mi][ni] = __builtin_amdgcn_mfma_f32_16x16x32_bf16(af[mi], bfr[ni], acc[mi][ni], 0, 0, 0); \
    asm volatile("s_waitcnt vmcnt(0)" ::: "memory");                                \
    __builtin_amdgcn_s_barrier();                                                   \
  }

  for (int t = 0; t < 128; t += 2) {
    long k1 = (long)(t + 1) * 64;
    long k2 = (long)(t + 2) * 64;
    GEMM_STEP(As0, Bs0, As1, Bs1, true, k1);          // tile t   (t+1 always < 128)
    GEMM_STEP(As1, Bs1, As0, Bs0, (t + 2 < 128), k2); // tile t+1
  }
#undef GEMM_STEP

  // NOTE on slot formula: ((wm*2+ks)*2+mi) == ks*2 + mi + wm*4 ; ((wn*2+ks)*4+ni) == ks*4 + ni + wn*8.

  // epilogue: +bias, relu, store bf16.  D: col=lane&15, row=(lane>>4)*4+reg
#pragma unroll
  for (int ni = 0; ni < 4; ni++) {
    int col = n0 + wn * 64 + ni * 16 + l15;
    float bias = fc_b[col];
#pragma unroll
    for (int mi = 0; mi < 2; mi++) {
      int rbase = m0 + wm * 32 + mi * 16 + lq * 4;
#pragma unroll
      for (int r = 0; r < 4; r++) {
        float v = acc[mi][ni][r] + bias;
        v = v > 0.f ? v : 0.f;
        h[(long)(rbase + r) * U0 + col] = f2bf(v);
      }
    }
  }
}

// ---------- kernel 5: selected-head MLP + epilogue ----------
__global__ __launch_bounds__(256) void head_kernel(const unsigned short* __restrict__ h,
                                                   const unsigned short* __restrict__ w1t,
                                                   const float* __restrict__ W1,
                                                   const float* __restrict__ b1,
                                                   const float* __restrict__ W2,
                                                   const float* __restrict__ b2,
                                                   const float* __restrict__ ego,
                                                   const int* __restrict__ idxlist,
                                                   const int* __restrict__ meta,
                                                   float* __restrict__ out) {
  int hd = blockIdx.y;
  int off = meta[hd];
  int cnt = meta[hd + 1] - off;
  int t0 = blockIdx.x * 32;
  if (t0 >= cnt) return;

  __shared__ int ridx[32];
  __shared__ float h1s[32][257];
  __shared__ float w2s[1024];  // W2[hd] preloaded: [256][4]
  int tid = threadIdx.x;
  if (tid < 32) {
    int i = t0 + tid;
    ridx[tid] = idxlist[off + (i < cnt ? i : 0)];
  }
  *(float4*)&w2s[tid * 4] = *(const float4*)(W2 + (long)hd * 1024 + tid * 4);
  __syncthreads();

  int lane = tid & 63, wave = tid >> 6;
  int l15 = lane & 15, lq = lane >> 4;

  long abase[2];
#pragma unroll
  for (int mi = 0; mi < 2; mi++) abase[mi] = (long)ridx[mi * 16 + l15] * U0 + lq * 8;
  long bbase[4];
#pragma unroll
  for (int ni = 0; ni < 4; ni++)
    bbase[ni] = (long)(hd * 256 + wave * 64 + ni * 16 + l15) * 1024 + lq * 8;

  f32x4 zero = {0.f, 0.f, 0.f, 0.f};
  f32x4 acc[2][4];
#pragma unroll
  for (int mi = 0; mi < 2; mi++)
#pragma unroll
    for (int ni = 0; ni < 4; ni++) acc[mi][ni] = zero;

#pragma unroll 2
  for (int k0 = 0; k0 < 1024; k0 += 32) {
    bf16x8 af[2], bfr[4];
#pragma unroll
    for (int mi = 0; mi < 2; mi++) af[mi] = *(const bf16x8*)(h + abase[mi] + k0);
#pragma unroll
    for (int ni = 0; ni < 4; ni++) bfr[ni] = *(const bf16x8*)(w1t + bbase[ni] + k0);
#pragma unroll
    for (int mi = 0; mi < 2; mi++)
#pragma unroll
      for (int ni = 0; ni < 4; ni++)
        acc[mi][ni] = __builtin_amdgcn_mfma_f32_16x16x32_bf16(af[mi], bfr[ni], acc[mi][ni], 0, 0, 0);
  }

  // ego contribution (fp32 exact) + bias + relu -> LDS
  const float* W1e = W1 + (long)hd * 1027 * 256 + (long)1024 * 256;  // rows 1024..1026
#pragma unroll
  for (int mi = 0; mi < 2; mi++)
#pragma unroll
    for (int r = 0; r < 4; r++) {
      int rl = mi * 16 + lq * 4 + r;
      int b = ridx[rl];
      float e0 = ego[b * 3 + 0], e1 = ego[b * 3 + 1], e2 = ego[b * 3 + 2];
#pragma unroll
      for (int ni = 0; ni < 4; ni++) {
        int col = wave * 64 + ni * 16 + l15;
        float v = acc[mi][ni][r] + b1[hd * 256 + col]
                + e0 * W1e[col] + e1 * W1e[256 + col] + e2 * W1e[512 + col];
        h1s[rl][col] = v > 0.f ? v : 0.f;
      }
    }
  __syncthreads();

  // h2 = h1 @ W2[hd] + b2[hd]; tanh/softplus epilogue; scatter by original row
  if (tid < 128) {
    int t = tid >> 2, o2 = tid & 3;
    if (t0 + t < cnt) {
      float s0 = 0.f, s1 = 0.f, s2 = 0.f, s3 = 0.f;
#pragma unroll 4
      for (int i = 0; i < 256; i += 4) {
        s0 += h1s[t][i + 0] * w2s[(i + 0) * 4 + o2];
        s1 += h1s[t][i + 1] * w2s[(i + 1) * 4 + o2];
        s2 += h1s[t][i + 2] * w2s[(i + 2) * 4 + o2];
        s3 += h1s[t][i + 3] * w2s[(i + 3) * 4 + o2];
      }
      float sum = b2[hd * 4 + o2] + ((s0 + s1) + (s2 + s3));
      int b = ridx[t];
      float res;
      if (o2 < 2) {
        res = 5.0f * tanhf(sum * 0.2f);
      } else {
        float z = sum + 4.99323838f;  // log(exp(5)-1)
        res = (z > 20.f ? z : log1pf(expf(z))) + 1e-4f;
      }
      out[b * 4 + o2] = res;
    }
  }
}

// ---------- launcher ----------
extern "C" void kernel_launch(void* const* d_in, const int* in_sizes, int n_in,
                              void* d_out, int out_size, void* d_ws, size_t ws_size,
                              hipStream_t stream) {
  const float* x   = (const float*)d_in[0];
  const int*   cmd = (const int*)d_in[1];
  const float* ego = (const float*)d_in[2];
  const float* fcW = (const float*)d_in[3];
  const float* fcb = (const float*)d_in[4];
  const float* W1  = (const float*)d_in[5];
  const float* b1  = (const float*)d_in[6];
  const float* W2  = (const float*)d_in[7];
  const float* b2  = (const float*)d_in[8];
  float* out = (float*)d_out;

  char* ws = (char*)d_ws;
  unsigned short* xb   = (unsigned short*)(ws);                 // 128 MB  x bf16
  unsigned short* wt   = (unsigned short*)(ws + 134217728);     // 16 MB   fc_W^T bf16
  unsigned short* hbuf = (unsigned short*)(ws + 150994944);     // 16 MB   h bf16
  unsigned short* w1t  = (unsigned short*)(ws + 167772160);     // 3 MB    W1^T bf16
  int* idxlist         = (int*)(ws + 170917888);                // 32 KB
  int* meta            = (int*)(ws + 170950656);                // 7 ints

  hipLaunchKernelGGL(cvt_x_kernel, dim3(2048), dim3(256), 0, stream, x, xb);
  hipLaunchKernelGGL(transpose_cvt_kernel, dim3(128, 16, 1), dim3(256), 0, stream,
                     fcW, wt, 8192, 1024, 0L, 0L);
  hipLaunchKernelGGL(transpose_cvt_kernel, dim3(16, 4, 6), dim3(256), 0, stream,
                     W1, w1t, 1024, 256, (long)1027 * 256, (long)256 * 1024);
  hipLaunchKernelGGL(bucket_kernel, dim3(1), dim3(1024), 0, stream, cmd, idxlist, meta);
  hipLaunchKernelGGL(gemm_kernel, dim3(512), dim3(512), 0, stream, xb, wt, fcb, hbuf);
  hipLaunchKernelGGL(head_kernel, dim3(256, 6), dim3(256), 0, stream,
                     hbuf, w1t, W1, b1, W2, b2, ego, idxlist, meta, out);
}